// Round 1
// baseline (6518.138 us; speedup 1.0000x reference)
//
#include <hip/hip_runtime.h>
#include <cstddef>

// ---------------- problem constants (match reference) ----------------
static constexpr int NP = 60000, NA = 30000;
static constexpr int EC = 300000, EW = 150000, EB = 150000;
static constexpr int IN_F = 1024, HID = 512, H = 4, D = 128, NCLS = 153;

// ---------------- CSR build ----------------
__global__ void hist_kernel(const int* __restrict__ dst, int E, int* __restrict__ counts) {
    int e = blockIdx.x * 256 + threadIdx.x;
    if (e < E) atomicAdd(&counts[dst[e]], 1);
}

// single-block exclusive scan, out has n+1 entries (out[n] = total)
__global__ void exscan_kernel(const int* __restrict__ in, int* __restrict__ out, int n) {
    __shared__ int wsum[4];
    int t = threadIdx.x;
    int lane = t & 63, w = t >> 6;
    int carry = 0;
    const int CH = 256 * 8;
    for (int base = 0; base < n; base += CH) {
        int v[8], run[8];
        int i0 = base + t * 8;
        int tsum = 0;
#pragma unroll
        for (int j = 0; j < 8; ++j) {
            int i = i0 + j;
            v[j] = (i < n) ? in[i] : 0;
            tsum += v[j];
            run[j] = tsum;
        }
        int x = tsum;
#pragma unroll
        for (int off = 1; off < 64; off <<= 1) {
            int y = __shfl_up(x, off);
            if (lane >= off) x += y;
        }
        if (lane == 63) wsum[w] = x;
        __syncthreads();
        int wpre = 0;
        for (int ww = 0; ww < w; ++ww) wpre += wsum[ww];
        int chunktot = wsum[0] + wsum[1] + wsum[2] + wsum[3];
        int pre = carry + wpre + (x - tsum);
#pragma unroll
        for (int j = 0; j < 8; ++j) {
            int i = i0 + j;
            if (i < n) out[i] = pre + run[j] - v[j];
        }
        carry += chunktot;
        __syncthreads();
    }
    if (t == 0) out[n] = carry;
}

__global__ void fill_kernel(const int* __restrict__ src, const int* __restrict__ dst, int E,
                            int* __restrict__ cursor, int* __restrict__ col) {
    int e = blockIdx.x * 256 + threadIdx.x;
    if (e < E) {
        int pos = atomicAdd(&cursor[dst[e]], 1);
        col[pos] = src[e];
    }
}

// ---------------- fp32 tiled GEMM: C[M,N] = A[M,K] @ B[K,(ldb)] (+bias) ----------------
#define BM 128
#define BN 128
#define BK 16
__device__ __forceinline__ int swz(int c) { return c + ((c >> 5) << 2); }

__global__ __launch_bounds__(256) void gemm_f32(
    const float* __restrict__ A, const float* __restrict__ B,
    const float* __restrict__ bias, float* __restrict__ C,
    int M, int K, int N, int ldb, int Nb, int ldc) {
    __shared__ float As[BK * 144];
    __shared__ float Bs[BK * 144];
    int tid = threadIdx.x;
    int bm = blockIdx.y * BM, bn = blockIdx.x * BN;
    int tx = tid & 15, ty = tid >> 4;
    float acc[8][8] = {};
    for (int kk = 0; kk < K; kk += BK) {
#pragma unroll
        for (int i = 0; i < 2; ++i) {
            int q = tid + i * 256;
            int r = q >> 2, c4 = (q & 3) << 2;
            int grow = bm + r;
            float4 v = make_float4(0.f, 0.f, 0.f, 0.f);
            if (grow < M) v = *(const float4*)(A + (size_t)grow * K + kk + c4);
            As[(c4 + 0) * 144 + swz(r)] = v.x;
            As[(c4 + 1) * 144 + swz(r)] = v.y;
            As[(c4 + 2) * 144 + swz(r)] = v.z;
            As[(c4 + 3) * 144 + swz(r)] = v.w;
        }
#pragma unroll
        for (int i = 0; i < 2; ++i) {
            int q = tid + i * 256;
            int r = q >> 5, c = (q & 31) << 2;
            int gcol = bn + c;
            float4 v = make_float4(0.f, 0.f, 0.f, 0.f);
            if (gcol + 3 < Nb) v = *(const float4*)(B + (size_t)(kk + r) * ldb + gcol);
            *(float4*)&Bs[r * 144 + swz(c)] = v;
        }
        __syncthreads();
#pragma unroll
        for (int k = 0; k < BK; ++k) {
            float a[8], b[8];
            *(float4*)&a[0] = *(const float4*)&As[k * 144 + swz(ty * 8)];
            *(float4*)&a[4] = *(const float4*)&As[k * 144 + swz(ty * 8) + 4];
            *(float4*)&b[0] = *(const float4*)&Bs[k * 144 + swz(tx * 8)];
            *(float4*)&b[4] = *(const float4*)&Bs[k * 144 + swz(tx * 8) + 4];
#pragma unroll
            for (int ii = 0; ii < 8; ++ii)
#pragma unroll
                for (int jj = 0; jj < 8; ++jj)
                    acc[ii][jj] += a[ii] * b[jj];
        }
        __syncthreads();
    }
#pragma unroll
    for (int ii = 0; ii < 8; ++ii) {
        int grow = bm + ty * 8 + ii;
        if (grow < M) {
#pragma unroll
            for (int jj = 0; jj < 8; jj += 4) {
                int gcol = bn + tx * 8 + jj;
                if (gcol + 3 < N && (ldc & 3) == 0) {
                    float4 o = make_float4(acc[ii][jj], acc[ii][jj + 1], acc[ii][jj + 2], acc[ii][jj + 3]);
                    if (bias) { o.x += bias[gcol]; o.y += bias[gcol + 1]; o.z += bias[gcol + 2]; o.w += bias[gcol + 3]; }
                    *(float4*)(C + (size_t)grow * ldc + gcol) = o;
                } else {
#pragma unroll
                    for (int u = 0; u < 4; ++u) {
                        int gc = gcol + u;
                        if (gc < N) C[(size_t)grow * ldc + gc] = acc[ii][jj + u] + (bias ? bias[gc] : 0.f);
                    }
                }
            }
        }
    }
}

// ---------------- el / er from z (one wave per row) ----------------
__global__ __launch_bounds__(256) void eler_kernel(
    const float* __restrict__ z, const float* __restrict__ al, const float* __restrict__ ar,
    float* __restrict__ el, float* __restrict__ er, int M) {
    int row = blockIdx.x * 4 + (threadIdx.x >> 6);
    int lane = threadIdx.x & 63;
    if (row >= M) return;
    const float4* zr = (const float4*)(z + (size_t)row * 512 + lane * 8);
    float4 z0 = zr[0], z1 = zr[1];
    const float4* alp = (const float4*)(al + lane * 8);
    float4 a0 = alp[0], a1 = alp[1];
    float s = z0.x * a0.x + z0.y * a0.y + z0.z * a0.z + z0.w * a0.w
            + z1.x * a1.x + z1.y * a1.y + z1.z * a1.z + z1.w * a1.w;
    s += __shfl_xor(s, 8); s += __shfl_xor(s, 4); s += __shfl_xor(s, 2); s += __shfl_xor(s, 1);
    int h = lane >> 4;
    if ((lane & 15) == 0) el[(size_t)row * 4 + h] = s;
    if (er) {
        const float4* arp = (const float4*)(ar + lane * 8);
        float4 b0 = arp[0], b1 = arp[1];
        float t = z0.x * b0.x + z0.y * b0.y + z0.z * b0.z + z0.w * b0.w
                + z1.x * b1.x + z1.y * b1.y + z1.z * b1.z + z1.w * b1.w;
        t += __shfl_xor(t, 8); t += __shfl_xor(t, 4); t += __shfl_xor(t, 2); t += __shfl_xor(t, 1);
        if ((lane & 15) == 0) er[(size_t)row * 4 + h] = t;
    }
}

// ---------------- fold: v[k,h] = sum_d W[k, h*128+d] * ar[h,d] ----------------
__global__ void fold_kernel(const float* __restrict__ W, const float* __restrict__ ar,
                            float* __restrict__ v, int K) {
    int i = blockIdx.x * 256 + threadIdx.x;
    if (i >= K * 4) return;
    int k = i >> 2, h = i & 3;
    const float* wr = W + (size_t)k * 512 + h * 128;
    const float* a = ar + h * 128;
    float s = 0.f;
#pragma unroll 4
    for (int d = 0; d < 128; ++d) s += wr[d] * a[d];
    v[i] = s;
}

// ---------------- skinny: er[M,4] = h[M,K] @ v[K,4] ----------------
__global__ __launch_bounds__(256) void skinny_kernel(
    const float* __restrict__ h, const float* __restrict__ v,
    float* __restrict__ er, int M, int K) {
    __shared__ float vs[4096];
    for (int i = threadIdx.x; i < K * 4; i += 256) vs[i] = v[i];
    __syncthreads();
    int row = blockIdx.x * 4 + (threadIdx.x >> 6);
    int lane = threadIdx.x & 63;
    if (row >= M) return;
    const float* hr = h + (size_t)row * K;
    float a0 = 0, a1 = 0, a2 = 0, a3 = 0;
    for (int k = lane; k < K; k += 64) {
        float x = hr[k];
        float4 vv = *(const float4*)&vs[k * 4];
        a0 += x * vv.x; a1 += x * vv.y; a2 += x * vv.z; a3 += x * vv.w;
    }
#pragma unroll
    for (int off = 32; off; off >>= 1) {
        a0 += __shfl_xor(a0, off); a1 += __shfl_xor(a1, off);
        a2 += __shfl_xor(a2, off); a3 += __shfl_xor(a3, off);
    }
    if (lane == 0) *(float4*)&er[(size_t)row * 4] = make_float4(a0, a1, a2, a3);
}

// ---------------- per-dst softmax stats (online) ----------------
__global__ void stats_kernel(const int* __restrict__ rp, const int* __restrict__ col,
                             const float* __restrict__ el, const float* __restrict__ er,
                             float* __restrict__ mo, float* __restrict__ so, int N) {
    int j = blockIdx.x * 256 + threadIdx.x;
    if (j >= N) return;
    int e0 = rp[j], e1 = rp[j + 1];
    float4 erv = *(const float4*)&er[(size_t)j * 4];
    float m[4] = {-INFINITY, -INFINITY, -INFINITY, -INFINITY};
    float s[4] = {0.f, 0.f, 0.f, 0.f};
    float erh[4] = {erv.x, erv.y, erv.z, erv.w};
    for (int e = e0; e < e1; ++e) {
        int src = col[e];
        float4 elv = *(const float4*)&el[(size_t)src * 4];
        float xs[4] = {elv.x, elv.y, elv.z, elv.w};
#pragma unroll
        for (int hh = 0; hh < 4; ++hh) {
            float x = xs[hh] + erh[hh];
            x = (x >= 0.f) ? x : 0.2f * x;
            float mn = fmaxf(m[hh], x);
            s[hh] = s[hh] * expf(m[hh] - mn) + expf(x - mn);
            m[hh] = mn;
        }
    }
    if (e0 == e1) { m[0] = m[1] = m[2] = m[3] = 0.f; }
    *(float4*)&mo[(size_t)j * 4] = make_float4(m[0], m[1], m[2], m[3]);
    *(float4*)&so[(size_t)j * 4] = make_float4(s[0], s[1], s[2], s[3]);
}

// ---------------- aggregation: one wave per dst node ----------------
__global__ __launch_bounds__(256) void agg_kernel(
    const int* __restrict__ rp, const int* __restrict__ col, const float* __restrict__ z,
    const float* __restrict__ el, const float* __restrict__ er,
    const float* __restrict__ mo, const float* __restrict__ so,
    float* __restrict__ out, int N, int accum) {
    int j = blockIdx.x * 4 + (threadIdx.x >> 6);
    int lane = threadIdx.x & 63;
    if (j >= N) return;
    int h = lane >> 4;
    float erh = er[(size_t)j * 4 + h];
    float mh = mo[(size_t)j * 4 + h];
    float inv = 1.0f / (so[(size_t)j * 4 + h] + 1e-9f);
    int e0 = rp[j], e1 = rp[j + 1];
    float4 acc0 = make_float4(0, 0, 0, 0), acc1 = make_float4(0, 0, 0, 0);
    for (int e = e0; e < e1; ++e) {
        int src = col[e];
        float x = el[(size_t)src * 4 + h] + erh;
        x = (x >= 0.f) ? x : 0.2f * x;
        float wgt = expf(x - mh) * inv;
        const float4* zr = (const float4*)(z + (size_t)src * 512 + lane * 8);
        float4 z0 = zr[0], z1 = zr[1];
        acc0.x += wgt * z0.x; acc0.y += wgt * z0.y; acc0.z += wgt * z0.z; acc0.w += wgt * z0.w;
        acc1.x += wgt * z1.x; acc1.y += wgt * z1.y; acc1.z += wgt * z1.z; acc1.w += wgt * z1.w;
    }
    float* op = out + (size_t)j * 512 + lane * 8;
    if (accum) {
        float4 o0 = *(float4*)op, o1 = *(float4*)(op + 4);
        acc0.x += o0.x; acc0.y += o0.y; acc0.z += o0.z; acc0.w += o0.w;
        acc1.x += o1.x; acc1.y += o1.y; acc1.z += o1.z; acc1.w += o1.w;
    }
    *(float4*)op = acc0;
    *(float4*)(op + 4) = acc1;
}

__global__ void relu_kernel(float4* __restrict__ x, int n4) {
    int i = blockIdx.x * 256 + threadIdx.x;
    if (i < n4) {
        float4 v = x[i];
        v.x = fmaxf(v.x, 0.f); v.y = fmaxf(v.y, 0.f);
        v.z = fmaxf(v.z, 0.f); v.w = fmaxf(v.w, 0.f);
        x[i] = v;
    }
}

__global__ void pad_kernel(const float* __restrict__ w, float* __restrict__ o) {
    int i = blockIdx.x * 256 + threadIdx.x;
    if (i >= 512 * 160) return;
    int r = i / 160, c = i % 160;
    o[i] = (c < NCLS) ? w[r * NCLS + c] : 0.f;
}

// ---------------- launcher ----------------
extern "C" void kernel_launch(void* const* d_in, const int* in_sizes, int n_in,
                              void* d_out, int out_size, void* d_ws, size_t ws_size,
                              hipStream_t stream) {
    const float* x_paper = (const float*)d_in[0];
    const float* x_author = (const float*)d_in[1];
    const int* cites_src = (const int*)d_in[2];
    const int* cites_dst = (const int*)d_in[3];
    const int* writes_src = (const int*)d_in[4];
    const int* writes_dst = (const int*)d_in[5];
    const int* wb_src = (const int*)d_in[6];
    const int* wb_dst = (const int*)d_in[7];
    const float* W0 = (const float*)d_in[8];
    const float* al0 = (const float*)d_in[9];
    const float* ar0 = (const float*)d_in[10];
    const float* W1 = (const float*)d_in[11];
    const float* al1 = (const float*)d_in[12];
    const float* ar1 = (const float*)d_in[13];
    const float* W2 = (const float*)d_in[14];
    const float* al2 = (const float*)d_in[15];
    const float* ar2 = (const float*)d_in[16];
    const float* linW = (const float*)d_in[17];
    const float* linb = (const float*)d_in[18];
    float* out = (float*)d_out;

    float* ws = (float*)d_ws;
    size_t off = 0;
    float* hpA = ws + off; off += (size_t)NP * 512;
    float* hpB = ws + off; off += (size_t)NP * 512;
    float* haA = ws + off; off += (size_t)NA * 512;
    float* haB = ws + off; off += (size_t)NA * 512;
    float* zbuf = ws + off; off += (size_t)NP * 512;
    float* el = ws + off; off += (size_t)NP * 4;
    float* er = ws + off; off += (size_t)NP * 4;
    float* mbuf = ws + off; off += (size_t)NP * 4;
    float* sbuf = ws + off; off += (size_t)NP * 4;
    float* vfold = ws + off; off += 4096;
    float* linWpad = ws + off; off += 512 * 160;
    int* ip = (int*)(ws + off);
    int* rp_c = ip; ip += NP + 1;
    int* col_c = ip; ip += EC;
    int* rp_w = ip; ip += NP + 1;
    int* col_w = ip; ip += EW;
    int* rp_b = ip; ip += NA + 1;
    int* col_b = ip; ip += EB;
    int* cursor = ip; ip += NP + 1;
    int* counts = ip; ip += NP;

    // ---- CSR build (per call; edge lists identical across calls) ----
    struct EdgeT { const int* src; const int* dst; int E; int n; int* rp; int* col; };
    EdgeT ets[3] = {
        {cites_src, cites_dst, EC, NP, rp_c, col_c},
        {writes_src, writes_dst, EW, NP, rp_w, col_w},
        {wb_src, wb_dst, EB, NA, rp_b, col_b},
    };
    for (int t = 0; t < 3; ++t) {
        hipMemsetAsync(counts, 0, (size_t)ets[t].n * 4, stream);
        hist_kernel<<<(ets[t].E + 255) / 256, 256, 0, stream>>>(ets[t].dst, ets[t].E, counts);
        exscan_kernel<<<1, 256, 0, stream>>>(counts, ets[t].rp, ets[t].n);
        hipMemcpyAsync(cursor, ets[t].rp, (size_t)ets[t].n * 4, hipMemcpyDeviceToDevice, stream);
        fill_kernel<<<(ets[t].E + 255) / 256, 256, 0, stream>>>(ets[t].src, ets[t].dst, ets[t].E, cursor, ets[t].col);
    }
    pad_kernel<<<320, 256, 0, stream>>>(linW, linWpad);

    auto gemm = [&](const float* A, const float* B, const float* bias, float* C,
                    int M, int K, int N, int ldb, int Nb, int ldc) {
        dim3 g((N + BN - 1) / BN, (M + BM - 1) / BM);
        gemm_f32<<<g, 256, 0, stream>>>(A, B, bias, C, M, K, N, ldb, Nb, ldc);
    };

    const float* Wl[3] = {W0, W1, W2};
    const float* alL[3] = {al0, al1, al2};
    const float* arL[3] = {ar0, ar1, ar2};
    const int Ks[3] = {IN_F, HID, HID};

    const float* hp = x_paper;
    const float* ha = x_author;
    for (int l = 0; l < 3; ++l) {
        int K = Ks[l];
        float* hp_n = (l & 1) ? hpB : hpA;
        float* ha_n = (l & 1) ? haB : haA;
        const float* W = Wl[l];
        const float* al = alL[l];
        const float* ar = arL[l];
        size_t wstride = (size_t)K * 512;

        // ---- t = 0: cites (paper -> paper) ----
        gemm(hp, W, nullptr, zbuf, NP, K, 512, 512, 512, 512);
        eler_kernel<<<(NP + 3) / 4, 256, 0, stream>>>(zbuf, al, ar, el, er, NP);
        stats_kernel<<<(NP + 255) / 256, 256, 0, stream>>>(rp_c, col_c, el, er, mbuf, sbuf, NP);
        agg_kernel<<<(NP + 3) / 4, 256, 0, stream>>>(rp_c, col_c, zbuf, el, er, mbuf, sbuf, hp_n, NP, 0);

        // ---- t = 1: writes (author -> paper) ----
        gemm(ha, W + wstride, nullptr, zbuf, NA, K, 512, 512, 512, 512);
        eler_kernel<<<(NA + 3) / 4, 256, 0, stream>>>(zbuf, al + 512, nullptr, el, nullptr, NA);
        fold_kernel<<<(K * 4 + 255) / 256, 256, 0, stream>>>(W + wstride, ar + 512, vfold, K);
        skinny_kernel<<<(NP + 3) / 4, 256, 0, stream>>>(hp, vfold, er, NP, K);
        stats_kernel<<<(NP + 255) / 256, 256, 0, stream>>>(rp_w, col_w, el, er, mbuf, sbuf, NP);
        agg_kernel<<<(NP + 3) / 4, 256, 0, stream>>>(rp_w, col_w, zbuf, el, er, mbuf, sbuf, hp_n, NP, 1);

        // ---- t = 2: wb (paper -> author) ----
        gemm(hp, W + 2 * wstride, nullptr, zbuf, NP, K, 512, 512, 512, 512);
        eler_kernel<<<(NP + 3) / 4, 256, 0, stream>>>(zbuf, al + 1024, nullptr, el, nullptr, NP);
        fold_kernel<<<(K * 4 + 255) / 256, 256, 0, stream>>>(W + 2 * wstride, ar + 1024, vfold, K);
        skinny_kernel<<<(NA + 3) / 4, 256, 0, stream>>>(ha, vfold, er, NA, K);
        stats_kernel<<<(NA + 255) / 256, 256, 0, stream>>>(rp_b, col_b, el, er, mbuf, sbuf, NA);
        agg_kernel<<<(NA + 3) / 4, 256, 0, stream>>>(rp_b, col_b, zbuf, el, er, mbuf, sbuf, ha_n, NA, 0);

        if (l < 2) {
            relu_kernel<<<((NP * 512 / 4) + 255) / 256, 256, 0, stream>>>((float4*)hp_n, NP * 512 / 4);
            relu_kernel<<<((NA * 512 / 4) + 255) / 256, 256, 0, stream>>>((float4*)ha_n, NA * 512 / 4);
        }
        hp = hp_n;
        ha = ha_n;
    }

    // ---- final linear: out = hp @ linW + linb ----
    gemm(hp, linWpad, linb, out, NP, HID, NCLS, 160, 160, NCLS);
}

// Round 2
// 4140.487 us; speedup vs baseline: 1.5742x; 1.5742x over previous
//
#include <hip/hip_runtime.h>
#include <cstddef>
#include <cstdint>

// ---------------- problem constants (match reference) ----------------
static constexpr int NP = 60000, NA = 30000;
static constexpr int EC = 300000, EW = 150000, EB = 150000;
static constexpr int IN_F = 1024, HID = 512, H = 4, D = 128, NCLS = 153;
static constexpr int MPAD_P = 60032;  // 469 * 128
static constexpr int MPAD_A = 30080;  // 235 * 128

typedef __attribute__((ext_vector_type(8))) short short8;
typedef __attribute__((ext_vector_type(4))) float float4v;

// ---------------- bf16 helpers (RNE) ----------------
__device__ __forceinline__ unsigned short f2bf(float f) {
    unsigned int u = __float_as_uint(f);
    unsigned int r = u + 0x7FFFu + ((u >> 16) & 1u);
    return (unsigned short)(r >> 16);
}
__device__ __forceinline__ float bf2f(unsigned short h) {
    return __uint_as_float(((unsigned int)h) << 16);
}

// async global->LDS, 16B per lane; lds base must be wave-uniform
__device__ __forceinline__ void gll16(const unsigned short* g, unsigned short* l) {
    __builtin_amdgcn_global_load_lds(
        (const __attribute__((address_space(1))) unsigned int*)g,
        (__attribute__((address_space(3))) unsigned int*)l, 16, 0, 0);
}

// ---------------- CSR build ----------------
__global__ void hist_kernel(const int* __restrict__ dst, int E, int* __restrict__ counts) {
    int e = blockIdx.x * 256 + threadIdx.x;
    if (e < E) atomicAdd(&counts[dst[e]], 1);
}

__global__ void exscan_kernel(const int* __restrict__ in, int* __restrict__ out, int n) {
    __shared__ int wsum[4];
    int t = threadIdx.x;
    int lane = t & 63, w = t >> 6;
    int carry = 0;
    const int CH = 256 * 8;
    for (int base = 0; base < n; base += CH) {
        int v[8], run[8];
        int i0 = base + t * 8;
        int tsum = 0;
#pragma unroll
        for (int j = 0; j < 8; ++j) {
            int i = i0 + j;
            v[j] = (i < n) ? in[i] : 0;
            tsum += v[j];
            run[j] = tsum;
        }
        int x = tsum;
#pragma unroll
        for (int off = 1; off < 64; off <<= 1) {
            int y = __shfl_up(x, off);
            if (lane >= off) x += y;
        }
        if (lane == 63) wsum[w] = x;
        __syncthreads();
        int wpre = 0;
        for (int ww = 0; ww < w; ++ww) wpre += wsum[ww];
        int chunktot = wsum[0] + wsum[1] + wsum[2] + wsum[3];
        int pre = carry + wpre + (x - tsum);
#pragma unroll
        for (int j = 0; j < 8; ++j) {
            int i = i0 + j;
            if (i < n) out[i] = pre + run[j] - v[j];
        }
        carry += chunktot;
        __syncthreads();
    }
    if (t == 0) out[n] = carry;
}

__global__ void fill_kernel(const int* __restrict__ src, const int* __restrict__ dst, int E,
                            int* __restrict__ cursor, int* __restrict__ col) {
    int e = blockIdx.x * 256 + threadIdx.x;
    if (e < E) {
        int pos = atomicAdd(&cursor[dst[e]], 1);
        col[pos] = src[e];
    }
}

// ---------------- split-bf16 prep ----------------
// decompose fp32 (M x K) into hi/lo bf16 (Mpad x K), zero pad rows; 4-wide
__global__ void decomp4_kernel(const float4* __restrict__ x, ushort4* __restrict__ hi,
                               ushort4* __restrict__ lo, int M, int K, int Mpad) {
    size_t i4 = (size_t)blockIdx.x * 256 + threadIdx.x;
    size_t tot = ((size_t)Mpad * K) >> 2;
    if (i4 >= tot) return;
    size_t row = (i4 * 4) / (size_t)K;
    float4 v = make_float4(0.f, 0.f, 0.f, 0.f);
    if (row < (size_t)M) v = x[i4];
    ushort4 h, l;
    h.x = f2bf(v.x); h.y = f2bf(v.y); h.z = f2bf(v.z); h.w = f2bf(v.w);
    l.x = f2bf(v.x - bf2f(h.x)); l.y = f2bf(v.y - bf2f(h.y));
    l.z = f2bf(v.z - bf2f(h.z)); l.w = f2bf(v.w - bf2f(h.w));
    hi[i4] = h; lo[i4] = l;
}

// B (K x N, ld=N) -> BT hi/lo (Npad x K), zero pad rows
__global__ void btprep_kernel(const float* __restrict__ W, unsigned short* __restrict__ hi,
                              unsigned short* __restrict__ lo, int K, int N, int Npad) {
    int i = blockIdx.x * 256 + threadIdx.x;
    if (i >= Npad * K) return;
    int n = i / K, k = i - n * K;
    float v = (n < N) ? W[(size_t)k * N + n] : 0.f;
    unsigned short h = f2bf(v);
    hi[i] = h;
    lo[i] = f2bf(v - bf2f(h));
}

// ---------------- MFMA split-bf16 GEMM ----------------
// C[M x Nstore] (ldc) = (Ahi+Alo)[M x K] @ (Bhi+Blo)^T[K x N] via 3 segments.
// A*: Mpad x K bf16 row-major. B*: Npad x K bf16 row-major (transposed weights).
// grid: (Npad/128, Mpad/128), 256 threads.
__global__ __launch_bounds__(256) void gemm_mfma(
    const unsigned short* __restrict__ Ahi, const unsigned short* __restrict__ Alo,
    const unsigned short* __restrict__ Bhi, const unsigned short* __restrict__ Blo,
    const float* __restrict__ bias, float* __restrict__ C,
    int M, int K, int Nstore, int ldc) {
    __shared__ unsigned short As[128 * 32];
    __shared__ unsigned short Bs[128 * 32];
    int tid = threadIdx.x;
    int lane = tid & 63, w = tid >> 6;
    int wr = w >> 1, wc = w & 1;
    int bm = blockIdx.y * 128, bn = blockIdx.x * 128;
    int sr = lane >> 2;          // row within 16-row group
    int sc = (lane & 3) * 8;     // element offset within 32-elem row

    float4v acc[4][4];
    float4v zf = {0.f, 0.f, 0.f, 0.f};
#pragma unroll
    for (int i = 0; i < 4; ++i)
#pragma unroll
        for (int j = 0; j < 4; ++j) acc[i][j] = zf;

    int arow = wr * 64 + (lane & 15);
    int brow = wc * 64 + (lane & 15);
    int koff = (lane >> 4) * 8;

#pragma unroll
    for (int s = 0; s < 3; ++s) {
        const unsigned short* Ap = (s == 1) ? Alo : Ahi;
        const unsigned short* Bp = (s == 2) ? Blo : Bhi;
        for (int kk = 0; kk < K; kk += 32) {
            // stage A tile (128 x 32) + B tile (128 x 32): 4 async 16B loads per wave
            gll16(Ap + (size_t)(bm + w * 16 + sr) * K + kk + sc, &As[w * 512]);
            gll16(Ap + (size_t)(bm + (w + 4) * 16 + sr) * K + kk + sc, &As[(w + 4) * 512]);
            gll16(Bp + (size_t)(bn + w * 16 + sr) * K + kk + sc, &Bs[w * 512]);
            gll16(Bp + (size_t)(bn + (w + 4) * 16 + sr) * K + kk + sc, &Bs[(w + 4) * 512]);
            __syncthreads();
            short8 af[4], bf[4];
#pragma unroll
            for (int i = 0; i < 4; ++i)
                af[i] = *(const short8*)&As[(arow + i * 16) * 32 + koff];
#pragma unroll
            for (int j = 0; j < 4; ++j)
                bf[j] = *(const short8*)&Bs[(brow + j * 16) * 32 + koff];
#pragma unroll
            for (int i = 0; i < 4; ++i)
#pragma unroll
                for (int j = 0; j < 4; ++j)
                    acc[i][j] = __builtin_amdgcn_mfma_f32_16x16x32_bf16(af[i], bf[j], acc[i][j], 0, 0, 0);
            __syncthreads();
        }
    }
    // epilogue: C/D layout col=lane&15, row=(lane>>4)*4+reg
    int col0 = bn + wc * 64 + (lane & 15);
    int row00 = bm + wr * 64 + (lane >> 4) * 4;
#pragma unroll
    for (int i = 0; i < 4; ++i) {
#pragma unroll
        for (int j = 0; j < 4; ++j) {
            int col = col0 + j * 16;
            if (col >= Nstore) continue;
            float badd = bias ? bias[col] : 0.f;
            int rowb = row00 + i * 16;
#pragma unroll
            for (int r = 0; r < 4; ++r) {
                int row = rowb + r;
                if (row < M) C[(size_t)row * ldc + col] = acc[i][j][r] + badd;
            }
        }
    }
}

// ---------------- fp32 tiled GEMM (fallback path) ----------------
#define BM 128
#define BN 128
#define BK 16
__device__ __forceinline__ int swz(int c) { return c + ((c >> 5) << 2); }

__global__ __launch_bounds__(256) void gemm_f32(
    const float* __restrict__ A, const float* __restrict__ B,
    const float* __restrict__ bias, float* __restrict__ C,
    int M, int K, int N, int ldb, int Nb, int ldc) {
    __shared__ float As[BK * 144];
    __shared__ float Bs[BK * 144];
    int tid = threadIdx.x;
    int bm = blockIdx.y * BM, bn = blockIdx.x * BN;
    int tx = tid & 15, ty = tid >> 4;
    float acc[8][8] = {};
    for (int kk = 0; kk < K; kk += BK) {
#pragma unroll
        for (int i = 0; i < 2; ++i) {
            int q = tid + i * 256;
            int r = q >> 2, c4 = (q & 3) << 2;
            int grow = bm + r;
            float4 v = make_float4(0.f, 0.f, 0.f, 0.f);
            if (grow < M) v = *(const float4*)(A + (size_t)grow * K + kk + c4);
            As[(c4 + 0) * 144 + swz(r)] = v.x;
            As[(c4 + 1) * 144 + swz(r)] = v.y;
            As[(c4 + 2) * 144 + swz(r)] = v.z;
            As[(c4 + 3) * 144 + swz(r)] = v.w;
        }
#pragma unroll
        for (int i = 0; i < 2; ++i) {
            int q = tid + i * 256;
            int r = q >> 5, c = (q & 31) << 2;
            int gcol = bn + c;
            float4 v = make_float4(0.f, 0.f, 0.f, 0.f);
            if (gcol + 3 < Nb) v = *(const float4*)(B + (size_t)(kk + r) * ldb + gcol);
            *(float4*)&Bs[r * 144 + swz(c)] = v;
        }
        __syncthreads();
#pragma unroll
        for (int k = 0; k < BK; ++k) {
            float a[8], b[8];
            *(float4*)&a[0] = *(const float4*)&As[k * 144 + swz(ty * 8)];
            *(float4*)&a[4] = *(const float4*)&As[k * 144 + swz(ty * 8) + 4];
            *(float4*)&b[0] = *(const float4*)&Bs[k * 144 + swz(tx * 8)];
            *(float4*)&b[4] = *(const float4*)&Bs[k * 144 + swz(tx * 8) + 4];
#pragma unroll
            for (int ii = 0; ii < 8; ++ii)
#pragma unroll
                for (int jj = 0; jj < 8; ++jj)
                    acc[ii][jj] += a[ii] * b[jj];
        }
        __syncthreads();
    }
#pragma unroll
    for (int ii = 0; ii < 8; ++ii) {
        int grow = bm + ty * 8 + ii;
        if (grow < M) {
#pragma unroll
            for (int jj = 0; jj < 8; jj += 4) {
                int gcol = bn + tx * 8 + jj;
                if (gcol + 3 < N && (ldc & 3) == 0) {
                    float4 o = make_float4(acc[ii][jj], acc[ii][jj + 1], acc[ii][jj + 2], acc[ii][jj + 3]);
                    if (bias) { o.x += bias[gcol]; o.y += bias[gcol + 1]; o.z += bias[gcol + 2]; o.w += bias[gcol + 3]; }
                    *(float4*)(C + (size_t)grow * ldc + gcol) = o;
                } else {
#pragma unroll
                    for (int u = 0; u < 4; ++u) {
                        int gc = gcol + u;
                        if (gc < N) C[(size_t)grow * ldc + gc] = acc[ii][jj + u] + (bias ? bias[gc] : 0.f);
                    }
                }
            }
        }
    }
}

// ---------------- el / er from z (one wave per row) ----------------
__global__ __launch_bounds__(256) void eler_kernel(
    const float* __restrict__ z, const float* __restrict__ al, const float* __restrict__ ar,
    float* __restrict__ el, float* __restrict__ er, int M) {
    int row = blockIdx.x * 4 + (threadIdx.x >> 6);
    int lane = threadIdx.x & 63;
    if (row >= M) return;
    const float4* zr = (const float4*)(z + (size_t)row * 512 + lane * 8);
    float4 z0 = zr[0], z1 = zr[1];
    const float4* alp = (const float4*)(al + lane * 8);
    float4 a0 = alp[0], a1 = alp[1];
    float s = z0.x * a0.x + z0.y * a0.y + z0.z * a0.z + z0.w * a0.w
            + z1.x * a1.x + z1.y * a1.y + z1.z * a1.z + z1.w * a1.w;
    s += __shfl_xor(s, 8); s += __shfl_xor(s, 4); s += __shfl_xor(s, 2); s += __shfl_xor(s, 1);
    int h = lane >> 4;
    if ((lane & 15) == 0) el[(size_t)row * 4 + h] = s;
    if (er) {
        const float4* arp = (const float4*)(ar + lane * 8);
        float4 b0 = arp[0], b1 = arp[1];
        float t = z0.x * b0.x + z0.y * b0.y + z0.z * b0.z + z0.w * b0.w
                + z1.x * b1.x + z1.y * b1.y + z1.z * b1.z + z1.w * b1.w;
        t += __shfl_xor(t, 8); t += __shfl_xor(t, 4); t += __shfl_xor(t, 2); t += __shfl_xor(t, 1);
        if ((lane & 15) == 0) er[(size_t)row * 4 + h] = t;
    }
}

// ---------------- fold: v[k,h] = sum_d W[k, h*128+d] * ar[h,d] ----------------
__global__ void fold_kernel(const float* __restrict__ W, const float* __restrict__ ar,
                            float* __restrict__ v, int K) {
    int i = blockIdx.x * 256 + threadIdx.x;
    if (i >= K * 4) return;
    int k = i >> 2, h = i & 3;
    const float* wr = W + (size_t)k * 512 + h * 128;
    const float* a = ar + h * 128;
    float s = 0.f;
#pragma unroll 4
    for (int d = 0; d < 128; ++d) s += wr[d] * a[d];
    v[i] = s;
}

// ---------------- skinny: er[M,4] = h[M,K] @ v[K,4] ----------------
__global__ __launch_bounds__(256) void skinny_kernel(
    const float* __restrict__ h, const float* __restrict__ v,
    float* __restrict__ er, int M, int K) {
    __shared__ float vs[4096];
    for (int i = threadIdx.x; i < K * 4; i += 256) vs[i] = v[i];
    __syncthreads();
    int row = blockIdx.x * 4 + (threadIdx.x >> 6);
    int lane = threadIdx.x & 63;
    if (row >= M) return;
    const float* hr = h + (size_t)row * K;
    float a0 = 0, a1 = 0, a2 = 0, a3 = 0;
    for (int k = lane; k < K; k += 64) {
        float x = hr[k];
        float4 vv = *(const float4*)&vs[k * 4];
        a0 += x * vv.x; a1 += x * vv.y; a2 += x * vv.z; a3 += x * vv.w;
    }
#pragma unroll
    for (int off = 32; off; off >>= 1) {
        a0 += __shfl_xor(a0, off); a1 += __shfl_xor(a1, off);
        a2 += __shfl_xor(a2, off); a3 += __shfl_xor(a3, off);
    }
    if (lane == 0) *(float4*)&er[(size_t)row * 4] = make_float4(a0, a1, a2, a3);
}

// ---------------- per-dst softmax stats (online) ----------------
__global__ void stats_kernel(const int* __restrict__ rp, const int* __restrict__ col,
                             const float* __restrict__ el, const float* __restrict__ er,
                             float* __restrict__ mo, float* __restrict__ so, int N) {
    int j = blockIdx.x * 256 + threadIdx.x;
    if (j >= N) return;
    int e0 = rp[j], e1 = rp[j + 1];
    float4 erv = *(const float4*)&er[(size_t)j * 4];
    float m[4] = {-INFINITY, -INFINITY, -INFINITY, -INFINITY};
    float s[4] = {0.f, 0.f, 0.f, 0.f};
    float erh[4] = {erv.x, erv.y, erv.z, erv.w};
    for (int e = e0; e < e1; ++e) {
        int src = col[e];
        float4 elv = *(const float4*)&el[(size_t)src * 4];
        float xs[4] = {elv.x, elv.y, elv.z, elv.w};
#pragma unroll
        for (int hh = 0; hh < 4; ++hh) {
            float x = xs[hh] + erh[hh];
            x = (x >= 0.f) ? x : 0.2f * x;
            float mn = fmaxf(m[hh], x);
            s[hh] = s[hh] * expf(m[hh] - mn) + expf(x - mn);
            m[hh] = mn;
        }
    }
    if (e0 == e1) { m[0] = m[1] = m[2] = m[3] = 0.f; }
    *(float4*)&mo[(size_t)j * 4] = make_float4(m[0], m[1], m[2], m[3]);
    *(float4*)&so[(size_t)j * 4] = make_float4(s[0], s[1], s[2], s[3]);
}

// ---------------- aggregation: one wave per dst node ----------------
__global__ __launch_bounds__(256) void agg_kernel(
    const int* __restrict__ rp, const int* __restrict__ col, const float* __restrict__ z,
    const float* __restrict__ el, const float* __restrict__ er,
    const float* __restrict__ mo, const float* __restrict__ so,
    float* __restrict__ out, int N, int accum) {
    int j = blockIdx.x * 4 + (threadIdx.x >> 6);
    int lane = threadIdx.x & 63;
    if (j >= N) return;
    int h = lane >> 4;
    float erh = er[(size_t)j * 4 + h];
    float mh = mo[(size_t)j * 4 + h];
    float inv = 1.0f / (so[(size_t)j * 4 + h] + 1e-9f);
    int e0 = rp[j], e1 = rp[j + 1];
    float4 acc0 = make_float4(0, 0, 0, 0), acc1 = make_float4(0, 0, 0, 0);
    for (int e = e0; e < e1; ++e) {
        int src = col[e];
        float x = el[(size_t)src * 4 + h] + erh;
        x = (x >= 0.f) ? x : 0.2f * x;
        float wgt = expf(x - mh) * inv;
        const float4* zr = (const float4*)(z + (size_t)src * 512 + lane * 8);
        float4 z0 = zr[0], z1 = zr[1];
        acc0.x += wgt * z0.x; acc0.y += wgt * z0.y; acc0.z += wgt * z0.z; acc0.w += wgt * z0.w;
        acc1.x += wgt * z1.x; acc1.y += wgt * z1.y; acc1.z += wgt * z1.z; acc1.w += wgt * z1.w;
    }
    float* op = out + (size_t)j * 512 + lane * 8;
    if (accum) {
        float4 o0 = *(float4*)op, o1 = *(float4*)(op + 4);
        acc0.x += o0.x; acc0.y += o0.y; acc0.z += o0.z; acc0.w += o0.w;
        acc1.x += o1.x; acc1.y += o1.y; acc1.z += o1.z; acc1.w += o1.w;
    }
    *(float4*)op = acc0;
    *(float4*)(op + 4) = acc1;
}

__global__ void relu_kernel(float4* __restrict__ x, int n4) {
    int i = blockIdx.x * 256 + threadIdx.x;
    if (i < n4) {
        float4 v = x[i];
        v.x = fmaxf(v.x, 0.f); v.y = fmaxf(v.y, 0.f);
        v.z = fmaxf(v.z, 0.f); v.w = fmaxf(v.w, 0.f);
        x[i] = v;
    }
}

__global__ void pad_kernel(const float* __restrict__ w, float* __restrict__ o) {
    int i = blockIdx.x * 256 + threadIdx.x;
    if (i >= 512 * 160) return;
    int r = i / 160, c = i % 160;
    o[i] = (c < NCLS) ? w[r * NCLS + c] : 0.f;
}

// ---------------- launcher ----------------
extern "C" void kernel_launch(void* const* d_in, const int* in_sizes, int n_in,
                              void* d_out, int out_size, void* d_ws, size_t ws_size,
                              hipStream_t stream) {
    const float* x_paper = (const float*)d_in[0];
    const float* x_author = (const float*)d_in[1];
    const int* cites_src = (const int*)d_in[2];
    const int* cites_dst = (const int*)d_in[3];
    const int* writes_src = (const int*)d_in[4];
    const int* writes_dst = (const int*)d_in[5];
    const int* wb_src = (const int*)d_in[6];
    const int* wb_dst = (const int*)d_in[7];
    const float* W0 = (const float*)d_in[8];
    const float* al0 = (const float*)d_in[9];
    const float* ar0 = (const float*)d_in[10];
    const float* W1 = (const float*)d_in[11];
    const float* al1 = (const float*)d_in[12];
    const float* ar1 = (const float*)d_in[13];
    const float* W2 = (const float*)d_in[14];
    const float* al2 = (const float*)d_in[15];
    const float* ar2 = (const float*)d_in[16];
    const float* linW = (const float*)d_in[17];
    const float* linb = (const float*)d_in[18];
    float* out = (float*)d_out;

    char* p = (char*)d_ws;
    auto alloc = [&](size_t n) { char* r = p; p += (n + 255) & ~(size_t)255; return r; };

    // common buffers
    float* hpA = (float*)alloc((size_t)NP * 512 * 4);
    float* hpB = (float*)alloc((size_t)NP * 512 * 4);
    float* haA = (float*)alloc((size_t)NA * 512 * 4);
    float* haB = (float*)alloc((size_t)NA * 512 * 4);
    float* zbuf = (float*)alloc((size_t)NP * 512 * 4);
    float* el = (float*)alloc((size_t)NP * 16);
    float* er = (float*)alloc((size_t)NP * 16);
    float* mbuf = (float*)alloc((size_t)NP * 16);
    float* sbuf = (float*)alloc((size_t)NP * 16);
    float* vfold = (float*)alloc(4096 * 4);
    float* linWpad = (float*)alloc(512 * 160 * 4);
    int* rp_c = (int*)alloc((NP + 1) * 4);
    int* col_c = (int*)alloc((size_t)EC * 4);
    int* rp_w = (int*)alloc((NP + 1) * 4);
    int* col_w = (int*)alloc((size_t)EW * 4);
    int* rp_b = (int*)alloc((NA + 1) * 4);
    int* col_b = (int*)alloc((size_t)EB * 4);
    int* cursor = (int*)alloc((NP + 1) * 4);
    int* counts = (int*)alloc((size_t)NP * 4);

    // MFMA-path extras
    unsigned short* AhiP = (unsigned short*)alloc((size_t)MPAD_P * 1024 * 2);
    unsigned short* AloP = (unsigned short*)alloc((size_t)MPAD_P * 1024 * 2);
    unsigned short* AhiA = (unsigned short*)alloc((size_t)MPAD_A * 1024 * 2);
    unsigned short* AloA = (unsigned short*)alloc((size_t)MPAD_A * 1024 * 2);
    const int Ks[3] = {IN_F, HID, HID};
    unsigned short *bthi[3][3], *btlo[3][3];
    for (int l = 0; l < 3; ++l)
        for (int t = 0; t < 3; ++t) {
            bthi[l][t] = (unsigned short*)alloc((size_t)512 * Ks[l] * 2);
            btlo[l][t] = (unsigned short*)alloc((size_t)512 * Ks[l] * 2);
        }
    unsigned short* btLhi = (unsigned short*)alloc((size_t)256 * 512 * 2);
    unsigned short* btLlo = (unsigned short*)alloc((size_t)256 * 512 * 2);
    size_t total_need = (size_t)(p - (char*)d_ws);
    bool use_mfma = ws_size >= total_need;

    // ---- CSR build (both paths) ----
    struct EdgeT { const int* src; const int* dst; int E; int n; int* rp; int* col; };
    EdgeT ets[3] = {
        {cites_src, cites_dst, EC, NP, rp_c, col_c},
        {writes_src, writes_dst, EW, NP, rp_w, col_w},
        {wb_src, wb_dst, EB, NA, rp_b, col_b},
    };
    for (int t = 0; t < 3; ++t) {
        hipMemsetAsync(counts, 0, (size_t)ets[t].n * 4, stream);
        hist_kernel<<<(ets[t].E + 255) / 256, 256, 0, stream>>>(ets[t].dst, ets[t].E, counts);
        exscan_kernel<<<1, 256, 0, stream>>>(counts, ets[t].rp, ets[t].n);
        hipMemcpyAsync(cursor, ets[t].rp, (size_t)ets[t].n * 4, hipMemcpyDeviceToDevice, stream);
        fill_kernel<<<(ets[t].E + 255) / 256, 256, 0, stream>>>(ets[t].src, ets[t].dst, ets[t].E, cursor, ets[t].col);
    }

    const float* Wl[3] = {W0, W1, W2};
    const float* alL[3] = {al0, al1, al2};
    const float* arL[3] = {ar0, ar1, ar2};

    if (use_mfma) {
        // ---- weight transpose + hi/lo decomposition (all up front) ----
        for (int l = 0; l < 3; ++l) {
            int K = Ks[l];
            for (int t = 0; t < 3; ++t)
                btprep_kernel<<<(512 * K + 255) / 256, 256, 0, stream>>>(
                    Wl[l] + (size_t)t * K * 512, bthi[l][t], btlo[l][t], K, 512, 512);
        }
        btprep_kernel<<<(256 * 512 + 255) / 256, 256, 0, stream>>>(linW, btLhi, btLlo, 512, NCLS, 256);

        // ---- layer-0 input decomposition ----
        decomp4_kernel<<<((size_t)MPAD_P * 1024 / 4 + 255) / 256, 256, 0, stream>>>(
            (const float4*)x_paper, (ushort4*)AhiP, (ushort4*)AloP, NP, 1024, MPAD_P);
        decomp4_kernel<<<((size_t)MPAD_A * 1024 / 4 + 255) / 256, 256, 0, stream>>>(
            (const float4*)x_author, (ushort4*)AhiA, (ushort4*)AloA, NA, 1024, MPAD_A);

        const float* hp = x_paper;
        const float* ha = x_author;
        for (int l = 0; l < 3; ++l) {
            int K = Ks[l];
            float* hp_n = (l & 1) ? hpB : hpA;
            float* ha_n = (l & 1) ? haB : haA;
            const float* W = Wl[l];
            const float* al = alL[l];
            const float* ar = arL[l];
            size_t wstride = (size_t)K * 512;
            dim3 gP(4, MPAD_P / 128), gA(4, MPAD_A / 128);

            // ---- t=0: cites (paper -> paper) ----
            gemm_mfma<<<gP, 256, 0, stream>>>(AhiP, AloP, bthi[l][0], btlo[l][0], nullptr, zbuf, NP, K, 512, 512);
            eler_kernel<<<(NP + 3) / 4, 256, 0, stream>>>(zbuf, al, ar, el, er, NP);
            stats_kernel<<<(NP + 255) / 256, 256, 0, stream>>>(rp_c, col_c, el, er, mbuf, sbuf, NP);
            agg_kernel<<<(NP + 3) / 4, 256, 0, stream>>>(rp_c, col_c, zbuf, el, er, mbuf, sbuf, hp_n, NP, 0);

            // ---- t=1: writes (author -> paper) ----
            gemm_mfma<<<gA, 256, 0, stream>>>(AhiA, AloA, bthi[l][1], btlo[l][1], nullptr, zbuf, NA, K, 512, 512);
            eler_kernel<<<(NA + 3) / 4, 256, 0, stream>>>(zbuf, al + 512, nullptr, el, nullptr, NA);
            fold_kernel<<<(K * 4 + 255) / 256, 256, 0, stream>>>(W + wstride, ar + 512, vfold, K);
            skinny_kernel<<<(NP + 3) / 4, 256, 0, stream>>>(hp, vfold, er, NP, K);
            stats_kernel<<<(NP + 255) / 256, 256, 0, stream>>>(rp_w, col_w, el, er, mbuf, sbuf, NP);
            agg_kernel<<<(NP + 3) / 4, 256, 0, stream>>>(rp_w, col_w, zbuf, el, er, mbuf, sbuf, hp_n, NP, 1);

            // ---- t=2: wb (paper -> author) ----
            gemm_mfma<<<gP, 256, 0, stream>>>(AhiP, AloP, bthi[l][2], btlo[l][2], nullptr, zbuf, NP, K, 512, 512);
            eler_kernel<<<(NP + 3) / 4, 256, 0, stream>>>(zbuf, al + 1024, nullptr, el, nullptr, NP);
            fold_kernel<<<(K * 4 + 255) / 256, 256, 0, stream>>>(W + 2 * wstride, ar + 1024, vfold, K);
            skinny_kernel<<<(NA + 3) / 4, 256, 0, stream>>>(ha, vfold, er, NA, K);
            stats_kernel<<<(NA + 255) / 256, 256, 0, stream>>>(rp_b, col_b, el, er, mbuf, sbuf, NA);
            agg_kernel<<<(NA + 3) / 4, 256, 0, stream>>>(rp_b, col_b, zbuf, el, er, mbuf, sbuf, ha_n, NA, 0);

            if (l < 2) {
                relu_kernel<<<((NP * 512 / 4) + 255) / 256, 256, 0, stream>>>((float4*)hp_n, NP * 512 / 4);
                relu_kernel<<<((NA * 512 / 4) + 255) / 256, 256, 0, stream>>>((float4*)ha_n, NA * 512 / 4);
            }
            // decompose next-layer activations (K=512)
            decomp4_kernel<<<((size_t)MPAD_P * 512 / 4 + 255) / 256, 256, 0, stream>>>(
                (const float4*)hp_n, (ushort4*)AhiP, (ushort4*)AloP, NP, 512, MPAD_P);
            if (l < 2)
                decomp4_kernel<<<((size_t)MPAD_A * 512 / 4 + 255) / 256, 256, 0, stream>>>(
                    (const float4*)ha_n, (ushort4*)AhiA, (ushort4*)AloA, NA, 512, MPAD_A);
            hp = hp_n;
            ha = ha_n;
        }
        // ---- final linear (MFMA, Npad=256) ----
        dim3 gL(2, MPAD_P / 128);
        gemm_mfma<<<gL, 256, 0, stream>>>(AhiP, AloP, btLhi, btLlo, linb, out, NP, 512, NCLS, NCLS);
    } else {
        // ---------------- fallback: round-1 fp32 path ----------------
        pad_kernel<<<320, 256, 0, stream>>>(linW, linWpad);
        auto gemm = [&](const float* A, const float* B, const float* bias, float* C,
                        int M, int K, int N, int ldb, int Nb, int ldc) {
            dim3 g((N + BN - 1) / BN, (M + BM - 1) / BM);
            gemm_f32<<<g, 256, 0, stream>>>(A, B, bias, C, M, K, N, ldb, Nb, ldc);
        };
        const float* hp = x_paper;
        const float* ha = x_author;
        for (int l = 0; l < 3; ++l) {
            int K = Ks[l];
            float* hp_n = (l & 1) ? hpB : hpA;
            float* ha_n = (l & 1) ? haB : haA;
            const float* W = Wl[l];
            const float* al = alL[l];
            const float* ar = arL[l];
            size_t wstride = (size_t)K * 512;

            gemm(hp, W, nullptr, zbuf, NP, K, 512, 512, 512, 512);
            eler_kernel<<<(NP + 3) / 4, 256, 0, stream>>>(zbuf, al, ar, el, er, NP);
            stats_kernel<<<(NP + 255) / 256, 256, 0, stream>>>(rp_c, col_c, el, er, mbuf, sbuf, NP);
            agg_kernel<<<(NP + 3) / 4, 256, 0, stream>>>(rp_c, col_c, zbuf, el, er, mbuf, sbuf, hp_n, NP, 0);

            gemm(ha, W + wstride, nullptr, zbuf, NA, K, 512, 512, 512, 512);
            eler_kernel<<<(NA + 3) / 4, 256, 0, stream>>>(zbuf, al + 512, nullptr, el, nullptr, NA);
            fold_kernel<<<(K * 4 + 255) / 256, 256, 0, stream>>>(W + wstride, ar + 512, vfold, K);
            skinny_kernel<<<(NP + 3) / 4, 256, 0, stream>>>(hp, vfold, er, NP, K);
            stats_kernel<<<(NP + 255) / 256, 256, 0, stream>>>(rp_w, col_w, el, er, mbuf, sbuf, NP);
            agg_kernel<<<(NP + 3) / 4, 256, 0, stream>>>(rp_w, col_w, zbuf, el, er, mbuf, sbuf, hp_n, NP, 1);

            gemm(hp, W + 2 * wstride, nullptr, zbuf, NP, K, 512, 512, 512, 512);
            eler_kernel<<<(NP + 3) / 4, 256, 0, stream>>>(zbuf, al + 1024, nullptr, el, nullptr, NP);
            fold_kernel<<<(K * 4 + 255) / 256, 256, 0, stream>>>(W + 2 * wstride, ar + 1024, vfold, K);
            skinny_kernel<<<(NA + 3) / 4, 256, 0, stream>>>(ha, vfold, er, NA, K);
            stats_kernel<<<(NA + 255) / 256, 256, 0, stream>>>(rp_b, col_b, el, er, mbuf, sbuf, NA);
            agg_kernel<<<(NA + 3) / 4, 256, 0, stream>>>(rp_b, col_b, zbuf, el, er, mbuf, sbuf, ha_n, NA, 0);

            if (l < 2) {
                relu_kernel<<<((NP * 512 / 4) + 255) / 256, 256, 0, stream>>>((float4*)hp_n, NP * 512 / 4);
                relu_kernel<<<((NA * 512 / 4) + 255) / 256, 256, 0, stream>>>((float4*)ha_n, NA * 512 / 4);
            }
            hp = hp_n;
            ha = ha_n;
        }
        gemm(hp, linWpad, linb, out, NP, HID, NCLS, 160, 160, NCLS);
    }
}

// Round 3
// 3364.318 us; speedup vs baseline: 1.9374x; 1.2307x over previous
//
#include <hip/hip_runtime.h>
#include <cstddef>
#include <cstdint>

// ---------------- problem constants (match reference) ----------------
static constexpr int NP = 60000, NA = 30000;
static constexpr int EC = 300000, EW = 150000, EB = 150000;
static constexpr int IN_F = 1024, HID = 512, H = 4, D = 128, NCLS = 153;
static constexpr int MPAD_P = 60032;  // 469 * 128
static constexpr int MPAD_A = 30080;  // 235 * 128

typedef __attribute__((ext_vector_type(8))) short short8;
typedef __attribute__((ext_vector_type(4))) float float4v;

// ---------------- bf16 helpers (RNE) ----------------
__device__ __forceinline__ unsigned short f2bf(float f) {
    unsigned int u = __float_as_uint(f);
    unsigned int r = u + 0x7FFFu + ((u >> 16) & 1u);
    return (unsigned short)(r >> 16);
}
__device__ __forceinline__ float bf2f(unsigned short h) {
    return __uint_as_float(((unsigned int)h) << 16);
}

// async global->LDS, 16B per lane; lds base must be wave-uniform
__device__ __forceinline__ void gll16(const unsigned short* g, unsigned short* l) {
    __builtin_amdgcn_global_load_lds(
        (const __attribute__((address_space(1))) unsigned int*)g,
        (__attribute__((address_space(3))) unsigned int*)l, 16, 0, 0);
}

// ---------------- CSR build ----------------
__global__ void hist_kernel(const int* __restrict__ dst, int E, int* __restrict__ counts) {
    int e = blockIdx.x * 256 + threadIdx.x;
    if (e < E) atomicAdd(&counts[dst[e]], 1);
}

__global__ void exscan_kernel(const int* __restrict__ in, int* __restrict__ out, int n) {
    __shared__ int wsum[4];
    int t = threadIdx.x;
    int lane = t & 63, w = t >> 6;
    int carry = 0;
    const int CH = 256 * 8;
    for (int base = 0; base < n; base += CH) {
        int v[8], run[8];
        int i0 = base + t * 8;
        int tsum = 0;
#pragma unroll
        for (int j = 0; j < 8; ++j) {
            int i = i0 + j;
            v[j] = (i < n) ? in[i] : 0;
            tsum += v[j];
            run[j] = tsum;
        }
        int x = tsum;
#pragma unroll
        for (int off = 1; off < 64; off <<= 1) {
            int y = __shfl_up(x, off);
            if (lane >= off) x += y;
        }
        if (lane == 63) wsum[w] = x;
        __syncthreads();
        int wpre = 0;
        for (int ww = 0; ww < w; ++ww) wpre += wsum[ww];
        int chunktot = wsum[0] + wsum[1] + wsum[2] + wsum[3];
        int pre = carry + wpre + (x - tsum);
#pragma unroll
        for (int j = 0; j < 8; ++j) {
            int i = i0 + j;
            if (i < n) out[i] = pre + run[j] - v[j];
        }
        carry += chunktot;
        __syncthreads();
    }
    if (t == 0) out[n] = carry;
}

__global__ void fill_kernel(const int* __restrict__ src, const int* __restrict__ dst, int E,
                            int* __restrict__ cursor, int* __restrict__ col) {
    int e = blockIdx.x * 256 + threadIdx.x;
    if (e < E) {
        int pos = atomicAdd(&cursor[dst[e]], 1);
        col[pos] = src[e];
    }
}

// ---------------- split-bf16 prep ----------------
__global__ void decomp4_kernel(const float4* __restrict__ x, ushort4* __restrict__ hi,
                               ushort4* __restrict__ lo, int M, int K, int Mpad) {
    size_t i4 = (size_t)blockIdx.x * 256 + threadIdx.x;
    size_t tot = ((size_t)Mpad * K) >> 2;
    if (i4 >= tot) return;
    size_t row = (i4 * 4) / (size_t)K;
    float4 v = make_float4(0.f, 0.f, 0.f, 0.f);
    if (row < (size_t)M) v = x[i4];
    ushort4 h, l;
    h.x = f2bf(v.x); h.y = f2bf(v.y); h.z = f2bf(v.z); h.w = f2bf(v.w);
    l.x = f2bf(v.x - bf2f(h.x)); l.y = f2bf(v.y - bf2f(h.y));
    l.z = f2bf(v.z - bf2f(h.z)); l.w = f2bf(v.w - bf2f(h.w));
    hi[i4] = h; lo[i4] = l;
}

// B (K x N, ld=N) -> BT hi/lo (Npad x K), zero pad rows
__global__ void btprep_kernel(const float* __restrict__ W, unsigned short* __restrict__ hi,
                              unsigned short* __restrict__ lo, int K, int N, int Npad) {
    int i = blockIdx.x * 256 + threadIdx.x;
    if (i >= Npad * K) return;
    int n = i / K, k = i - n * K;
    float v = (n < N) ? W[(size_t)k * N + n] : 0.f;
    unsigned short h = f2bf(v);
    hi[i] = h;
    lo[i] = f2bf(v - bf2f(h));
}

// ---------------- MFMA split-bf16 GEMM, combined K-pass ----------------
// C[M x Nstore](ldc) = (Ahi+Alo)[MxK] @ (Bhi+Blo)^T with 3 MFMA terms
// (hi*hi + lo*hi + hi*lo) in ONE K sweep. Tiles: BM=128, BN=256, BK=32.
// grid: (Npad/256, Mpad/128), 256 threads (4 waves, 2x2).
__global__ __launch_bounds__(256, 2) void gemm_mfma3(
    const unsigned short* __restrict__ Ahi, const unsigned short* __restrict__ Alo,
    const unsigned short* __restrict__ Bhi, const unsigned short* __restrict__ Blo,
    const float* __restrict__ bias, float* __restrict__ C,
    int M, int K, int Nstore, int ldc) {
    __shared__ unsigned short Ash[128 * 32];
    __shared__ unsigned short Asl[128 * 32];
    __shared__ unsigned short Bsh[256 * 32];
    __shared__ unsigned short Bsl[256 * 32];
    int tid = threadIdx.x;
    int lane = tid & 63, w = tid >> 6;
    int wr = w >> 1, wc = w & 1;
    int bm = blockIdx.y * 128, bn = blockIdx.x * 256;
    int sr = lane >> 2;        // row within 16-row staging group
    int sc = (lane & 3) * 8;   // elem offset within 32-elem row

    float4v acc[4][8];
    float4v zf = {0.f, 0.f, 0.f, 0.f};
#pragma unroll
    for (int i = 0; i < 4; ++i)
#pragma unroll
        for (int j = 0; j < 8; ++j) acc[i][j] = zf;

    int arow = wr * 64 + (lane & 15);
    int brow = wc * 128 + (lane & 15);
    int koff = (lane >> 4) * 8;

    for (int kk = 0; kk < K; kk += 32) {
        size_t a0 = (size_t)(bm + w * 16 + sr) * K + kk + sc;
        size_t a1 = (size_t)(bm + (w + 4) * 16 + sr) * K + kk + sc;
        gll16(Ahi + a0, &Ash[w * 512]);
        gll16(Ahi + a1, &Ash[(w + 4) * 512]);
        gll16(Alo + a0, &Asl[w * 512]);
        gll16(Alo + a1, &Asl[(w + 4) * 512]);
#pragma unroll
        for (int c = 0; c < 4; ++c) {
            size_t b0 = (size_t)(bn + (w + 4 * c) * 16 + sr) * K + kk + sc;
            gll16(Bhi + b0, &Bsh[(w + 4 * c) * 512]);
            gll16(Blo + b0, &Bsl[(w + 4 * c) * 512]);
        }
        __syncthreads();
        short8 fa[4], fb[8], fl[4];
#pragma unroll
        for (int i = 0; i < 4; ++i)
            fa[i] = *(const short8*)&Ash[(arow + i * 16) * 32 + koff];
#pragma unroll
        for (int j = 0; j < 8; ++j)
            fb[j] = *(const short8*)&Bsh[(brow + j * 16) * 32 + koff];
        // seg0: hi * hi
#pragma unroll
        for (int i = 0; i < 4; ++i)
#pragma unroll
            for (int j = 0; j < 8; ++j)
                acc[i][j] = __builtin_amdgcn_mfma_f32_16x16x32_bf16(fa[i], fb[j], acc[i][j], 0, 0, 0);
        // seg1: lo * hi
#pragma unroll
        for (int i = 0; i < 4; ++i)
            fl[i] = *(const short8*)&Asl[(arow + i * 16) * 32 + koff];
#pragma unroll
        for (int i = 0; i < 4; ++i)
#pragma unroll
            for (int j = 0; j < 8; ++j)
                acc[i][j] = __builtin_amdgcn_mfma_f32_16x16x32_bf16(fl[i], fb[j], acc[i][j], 0, 0, 0);
        // seg2: hi * lo (reuse fb regs)
#pragma unroll
        for (int j = 0; j < 8; ++j)
            fb[j] = *(const short8*)&Bsl[(brow + j * 16) * 32 + koff];
#pragma unroll
        for (int i = 0; i < 4; ++i)
#pragma unroll
            for (int j = 0; j < 8; ++j)
                acc[i][j] = __builtin_amdgcn_mfma_f32_16x16x32_bf16(fa[i], fb[j], acc[i][j], 0, 0, 0);
        __syncthreads();
    }
    // epilogue: C/D layout col=lane&15, row=(lane>>4)*4+reg
    int col0 = bn + wc * 128 + (lane & 15);
    int row00 = bm + wr * 64 + (lane >> 4) * 4;
#pragma unroll
    for (int i = 0; i < 4; ++i) {
#pragma unroll
        for (int j = 0; j < 8; ++j) {
            int col = col0 + j * 16;
            if (col >= Nstore) continue;
            float badd = bias ? bias[col] : 0.f;
            int rowb = row00 + i * 16;
#pragma unroll
            for (int r = 0; r < 4; ++r) {
                int row = rowb + r;
                if (row < M) C[(size_t)row * ldc + col] = acc[i][j][r] + badd;
            }
        }
    }
}

// ---------------- el / er from z (one wave per row) ----------------
__global__ __launch_bounds__(256) void eler_kernel(
    const float* __restrict__ z, const float* __restrict__ al, const float* __restrict__ ar,
    float* __restrict__ el, float* __restrict__ er, int M) {
    int row = blockIdx.x * 4 + (threadIdx.x >> 6);
    int lane = threadIdx.x & 63;
    if (row >= M) return;
    const float4* zr = (const float4*)(z + (size_t)row * 512 + lane * 8);
    float4 z0 = zr[0], z1 = zr[1];
    const float4* alp = (const float4*)(al + lane * 8);
    float4 a0 = alp[0], a1 = alp[1];
    float s = z0.x * a0.x + z0.y * a0.y + z0.z * a0.z + z0.w * a0.w
            + z1.x * a1.x + z1.y * a1.y + z1.z * a1.z + z1.w * a1.w;
    s += __shfl_xor(s, 8); s += __shfl_xor(s, 4); s += __shfl_xor(s, 2); s += __shfl_xor(s, 1);
    int h = lane >> 4;
    if ((lane & 15) == 0) el[(size_t)row * 4 + h] = s;
    if (er) {
        const float4* arp = (const float4*)(ar + lane * 8);
        float4 b0 = arp[0], b1 = arp[1];
        float t = z0.x * b0.x + z0.y * b0.y + z0.z * b0.z + z0.w * b0.w
                + z1.x * b1.x + z1.y * b1.y + z1.z * b1.z + z1.w * b1.w;
        t += __shfl_xor(t, 8); t += __shfl_xor(t, 4); t += __shfl_xor(t, 2); t += __shfl_xor(t, 1);
        if ((lane & 15) == 0) er[(size_t)row * 4 + h] = t;
    }
}

// ---------------- fold: v[k,h] = sum_d W[k, h*128+d] * ar[h,d] ----------------
__global__ void fold_kernel(const float* __restrict__ W, const float* __restrict__ ar,
                            float* __restrict__ v, int K) {
    int i = blockIdx.x * 256 + threadIdx.x;
    if (i >= K * 4) return;
    int k = i >> 2, h = i & 3;
    const float* wr = W + (size_t)k * 512 + h * 128;
    const float* a = ar + h * 128;
    float s = 0.f;
#pragma unroll 4
    for (int d = 0; d < 128; ++d) s += wr[d] * a[d];
    v[i] = s;
}

// ---------------- skinny: er[M,4] = h[M,K] @ v[K,4] ----------------
__global__ __launch_bounds__(256) void skinny_kernel(
    const float* __restrict__ h, const float* __restrict__ v,
    float* __restrict__ er, int M, int K) {
    __shared__ float vs[4096];
    for (int i = threadIdx.x; i < K * 4; i += 256) vs[i] = v[i];
    __syncthreads();
    int row = blockIdx.x * 4 + (threadIdx.x >> 6);
    int lane = threadIdx.x & 63;
    if (row >= M) return;
    const float* hr = h + (size_t)row * K;
    float a0 = 0, a1 = 0, a2 = 0, a3 = 0;
    for (int k = lane; k < K; k += 64) {
        float x = hr[k];
        float4 vv = *(const float4*)&vs[k * 4];
        a0 += x * vv.x; a1 += x * vv.y; a2 += x * vv.z; a3 += x * vv.w;
    }
#pragma unroll
    for (int off = 32; off; off >>= 1) {
        a0 += __shfl_xor(a0, off); a1 += __shfl_xor(a1, off);
        a2 += __shfl_xor(a2, off); a3 += __shfl_xor(a3, off);
    }
    if (lane == 0) *(float4*)&er[(size_t)row * 4] = make_float4(a0, a1, a2, a3);
}

// ---------------- fused softmax-stats + aggregation (+relu +decomp) ----------------
// One wave per dst node. Type-1 edges mandatory, type-2 optional (rp2 != null).
// Each GAT softmax is per edge type; results summed (HeteroGraphConv 'sum').
__global__ __launch_bounds__(256) void agg_fused(
    const int* __restrict__ rp1, const int* __restrict__ col1, const float* __restrict__ z1,
    const float* __restrict__ el1, const float* __restrict__ er1,
    const int* __restrict__ rp2, const int* __restrict__ col2, const float* __restrict__ z2,
    const float* __restrict__ el2, const float* __restrict__ er2,
    float* __restrict__ out, unsigned short* __restrict__ hi, unsigned short* __restrict__ lo,
    int N, int do_relu) {
    int j = blockIdx.x * 4 + (threadIdx.x >> 6);
    int lane = threadIdx.x & 63;
    if (j >= N) return;
    int h = lane >> 4;
    float4 acc0 = make_float4(0, 0, 0, 0), acc1 = make_float4(0, 0, 0, 0);

    // ---- type 1 ----
    {
        int e0 = rp1[j], e1 = rp1[j + 1];
        float erh = er1[(size_t)j * 4 + h];
        float m = -INFINITY, s = 0.f;
        for (int e = e0; e < e1; ++e) {
            float x = el1[(size_t)col1[e] * 4 + h] + erh;
            x = (x >= 0.f) ? x : 0.2f * x;
            float mn = fmaxf(m, x);
            s = s * expf(m - mn) + expf(x - mn);
            m = mn;
        }
        float inv = 1.0f / (s + 1e-9f);
        for (int e = e0; e < e1; ++e) {
            int src = col1[e];
            float x = el1[(size_t)src * 4 + h] + erh;
            x = (x >= 0.f) ? x : 0.2f * x;
            float wgt = expf(x - m) * inv;
            const float4* zr = (const float4*)(z1 + (size_t)src * 512 + lane * 8);
            float4 za = zr[0], zb = zr[1];
            acc0.x += wgt * za.x; acc0.y += wgt * za.y; acc0.z += wgt * za.z; acc0.w += wgt * za.w;
            acc1.x += wgt * zb.x; acc1.y += wgt * zb.y; acc1.z += wgt * zb.z; acc1.w += wgt * zb.w;
        }
    }
    // ---- type 2 (optional) ----
    if (rp2) {
        int e0 = rp2[j], e1 = rp2[j + 1];
        float erh = er2[(size_t)j * 4 + h];
        float m = -INFINITY, s = 0.f;
        for (int e = e0; e < e1; ++e) {
            float x = el2[(size_t)col2[e] * 4 + h] + erh;
            x = (x >= 0.f) ? x : 0.2f * x;
            float mn = fmaxf(m, x);
            s = s * expf(m - mn) + expf(x - mn);
            m = mn;
        }
        float inv = 1.0f / (s + 1e-9f);
        for (int e = e0; e < e1; ++e) {
            int src = col2[e];
            float x = el2[(size_t)src * 4 + h] + erh;
            x = (x >= 0.f) ? x : 0.2f * x;
            float wgt = expf(x - m) * inv;
            const float4* zr = (const float4*)(z2 + (size_t)src * 512 + lane * 8);
            float4 za = zr[0], zb = zr[1];
            acc0.x += wgt * za.x; acc0.y += wgt * za.y; acc0.z += wgt * za.z; acc0.w += wgt * za.w;
            acc1.x += wgt * zb.x; acc1.y += wgt * zb.y; acc1.z += wgt * zb.z; acc1.w += wgt * zb.w;
        }
    }
    if (do_relu) {
        acc0.x = fmaxf(acc0.x, 0.f); acc0.y = fmaxf(acc0.y, 0.f);
        acc0.z = fmaxf(acc0.z, 0.f); acc0.w = fmaxf(acc0.w, 0.f);
        acc1.x = fmaxf(acc1.x, 0.f); acc1.y = fmaxf(acc1.y, 0.f);
        acc1.z = fmaxf(acc1.z, 0.f); acc1.w = fmaxf(acc1.w, 0.f);
    }
    float* op = out + (size_t)j * 512 + lane * 8;
    *(float4*)op = acc0;
    *(float4*)(op + 4) = acc1;
    if (hi) {
        size_t base = (size_t)j * 512 + lane * 8;
        ushort4 h0, h1, l0, l1;
        h0.x = f2bf(acc0.x); h0.y = f2bf(acc0.y); h0.z = f2bf(acc0.z); h0.w = f2bf(acc0.w);
        h1.x = f2bf(acc1.x); h1.y = f2bf(acc1.y); h1.z = f2bf(acc1.z); h1.w = f2bf(acc1.w);
        l0.x = f2bf(acc0.x - bf2f(h0.x)); l0.y = f2bf(acc0.y - bf2f(h0.y));
        l0.z = f2bf(acc0.z - bf2f(h0.z)); l0.w = f2bf(acc0.w - bf2f(h0.w));
        l1.x = f2bf(acc1.x - bf2f(h1.x)); l1.y = f2bf(acc1.y - bf2f(h1.y));
        l1.z = f2bf(acc1.z - bf2f(h1.z)); l1.w = f2bf(acc1.w - bf2f(h1.w));
        *(ushort4*)(hi + base) = h0;
        *(ushort4*)(hi + base + 4) = h1;
        *(ushort4*)(lo + base) = l0;
        *(ushort4*)(lo + base + 4) = l1;
    }
}

// ---------------- launcher ----------------
extern "C" void kernel_launch(void* const* d_in, const int* in_sizes, int n_in,
                              void* d_out, int out_size, void* d_ws, size_t ws_size,
                              hipStream_t stream) {
    const float* x_paper = (const float*)d_in[0];
    const float* x_author = (const float*)d_in[1];
    const int* cites_src = (const int*)d_in[2];
    const int* cites_dst = (const int*)d_in[3];
    const int* writes_src = (const int*)d_in[4];
    const int* writes_dst = (const int*)d_in[5];
    const int* wb_src = (const int*)d_in[6];
    const int* wb_dst = (const int*)d_in[7];
    const float* W0 = (const float*)d_in[8];
    const float* al0 = (const float*)d_in[9];
    const float* ar0 = (const float*)d_in[10];
    const float* W1 = (const float*)d_in[11];
    const float* al1 = (const float*)d_in[12];
    const float* ar1 = (const float*)d_in[13];
    const float* W2 = (const float*)d_in[14];
    const float* al2 = (const float*)d_in[15];
    const float* ar2 = (const float*)d_in[16];
    const float* linW = (const float*)d_in[17];
    const float* linb = (const float*)d_in[18];
    float* out = (float*)d_out;

    char* p = (char*)d_ws;
    auto alloc = [&](size_t n) { char* r = p; p += (n + 255) & ~(size_t)255; return r; };

    float* hpA = (float*)alloc((size_t)NP * 512 * 4);
    float* hpB = (float*)alloc((size_t)NP * 512 * 4);
    float* haA = (float*)alloc((size_t)NA * 512 * 4);
    float* haB = (float*)alloc((size_t)NA * 512 * 4);
    float* zbuf = (float*)alloc((size_t)NP * 512 * 4);   // paper-source z
    float* elA = (float*)alloc((size_t)NP * 16);
    float* erA = (float*)alloc((size_t)NP * 16);
    float* elB = (float*)alloc((size_t)NP * 16);
    float* erB = (float*)alloc((size_t)NP * 16);
    float* vfold = (float*)alloc(4096 * 4);
    int* rp_c = (int*)alloc((NP + 1) * 4);
    int* col_c = (int*)alloc((size_t)EC * 4);
    int* rp_w = (int*)alloc((NP + 1) * 4);
    int* col_w = (int*)alloc((size_t)EW * 4);
    int* rp_b = (int*)alloc((NA + 1) * 4);
    int* col_b = (int*)alloc((size_t)EB * 4);
    int* cursor = (int*)alloc((NP + 1) * 4);
    int* counts = (int*)alloc((size_t)NP * 4);

    unsigned short* AhiP = (unsigned short*)alloc((size_t)MPAD_P * 1024 * 2);
    unsigned short* AloP = (unsigned short*)alloc((size_t)MPAD_P * 1024 * 2);
    unsigned short* AhiA = (unsigned short*)alloc((size_t)MPAD_A * 1024 * 2);
    unsigned short* AloA = (unsigned short*)alloc((size_t)MPAD_A * 1024 * 2);
    const int Ks[3] = {IN_F, HID, HID};
    unsigned short *bthi[3][3], *btlo[3][3];
    for (int l = 0; l < 3; ++l)
        for (int t = 0; t < 3; ++t) {
            bthi[l][t] = (unsigned short*)alloc((size_t)512 * Ks[l] * 2);
            btlo[l][t] = (unsigned short*)alloc((size_t)512 * Ks[l] * 2);
        }
    unsigned short* btLhi = (unsigned short*)alloc((size_t)256 * 512 * 2);
    unsigned short* btLlo = (unsigned short*)alloc((size_t)256 * 512 * 2);
    (void)ws_size;

    // ---- CSR build ----
    struct EdgeT { const int* src; const int* dst; int E; int n; int* rp; int* col; };
    EdgeT ets[3] = {
        {cites_src, cites_dst, EC, NP, rp_c, col_c},
        {writes_src, writes_dst, EW, NP, rp_w, col_w},
        {wb_src, wb_dst, EB, NA, rp_b, col_b},
    };
    for (int t = 0; t < 3; ++t) {
        hipMemsetAsync(counts, 0, (size_t)ets[t].n * 4, stream);
        hist_kernel<<<(ets[t].E + 255) / 256, 256, 0, stream>>>(ets[t].dst, ets[t].E, counts);
        exscan_kernel<<<1, 256, 0, stream>>>(counts, ets[t].rp, ets[t].n);
        hipMemcpyAsync(cursor, ets[t].rp, (size_t)ets[t].n * 4, hipMemcpyDeviceToDevice, stream);
        fill_kernel<<<(ets[t].E + 255) / 256, 256, 0, stream>>>(ets[t].src, ets[t].dst, ets[t].E, cursor, ets[t].col);
    }

    const float* Wl[3] = {W0, W1, W2};
    const float* alL[3] = {al0, al1, al2};
    const float* arL[3] = {ar0, ar1, ar2};

    // ---- weight transpose + hi/lo decomposition ----
    for (int l = 0; l < 3; ++l) {
        int K = Ks[l];
        for (int t = 0; t < 3; ++t)
            btprep_kernel<<<(512 * K + 255) / 256, 256, 0, stream>>>(
                Wl[l] + (size_t)t * K * 512, bthi[l][t], btlo[l][t], K, 512, 512);
    }
    btprep_kernel<<<(256 * 512 + 255) / 256, 256, 0, stream>>>(linW, btLhi, btLlo, 512, NCLS, 256);

    // ---- layer-0 input decomposition ----
    decomp4_kernel<<<((size_t)MPAD_P * 1024 / 4 + 255) / 256, 256, 0, stream>>>(
        (const float4*)x_paper, (ushort4*)AhiP, (ushort4*)AloP, NP, 1024, MPAD_P);
    decomp4_kernel<<<((size_t)MPAD_A * 1024 / 4 + 255) / 256, 256, 0, stream>>>(
        (const float4*)x_author, (ushort4*)AhiA, (ushort4*)AloA, NA, 1024, MPAD_A);

    auto gemm = [&](const unsigned short* Ah, const unsigned short* Al,
                    const unsigned short* Bh, const unsigned short* Bl,
                    const float* bias, float* C, int M, int Mpad, int K, int gx,
                    int Nstore, int ldc) {
        dim3 g(gx, Mpad / 128);
        gemm_mfma3<<<g, 256, 0, stream>>>(Ah, Al, Bh, Bl, bias, C, M, K, Nstore, ldc);
    };

    const float* hp = x_paper;
    const float* ha = x_author;
    for (int l = 0; l < 3; ++l) {
        int K = Ks[l];
        float* hp_n = (l & 1) ? hpB : hpA;
        float* ha_n = (l & 1) ? haB : haA;
        float* zbuf_w = ha_n;  // alias: dead before agg_author writes ha_n
        const float* W = Wl[l];
        const float* al = alL[l];
        const float* ar = arL[l];
        size_t wstride = (size_t)K * 512;
        int relu = (l < 2) ? 1 : 0;

        // t0 (cites, paper z) and t1 (writes, author z) GEMMs
        gemm(AhiP, AloP, bthi[l][0], btlo[l][0], nullptr, zbuf, NP, MPAD_P, K, 2, 512, 512);
        gemm(AhiA, AloA, bthi[l][1], btlo[l][1], nullptr, zbuf_w, NA, MPAD_A, K, 2, 512, 512);
        // attention logits
        eler_kernel<<<(NP + 3) / 4, 256, 0, stream>>>(zbuf, al, ar, elA, erA, NP);
        eler_kernel<<<(NA + 3) / 4, 256, 0, stream>>>(zbuf_w, al + 512, nullptr, elB, nullptr, NA);
        fold_kernel<<<(K * 4 + 255) / 256, 256, 0, stream>>>(W + wstride, ar + 512, vfold, K);
        skinny_kernel<<<(NP + 3) / 4, 256, 0, stream>>>(hp, vfold, erB, NP, K);
        // paper aggregation: cites + writes fused (+relu)
        agg_fused<<<(NP + 3) / 4, 256, 0, stream>>>(
            rp_c, col_c, zbuf, elA, erA,
            rp_w, col_w, zbuf_w, elB, erB,
            hp_n, nullptr, nullptr, NP, relu);
        // t2 (wb, paper z) GEMM — must read old AhiP before decomp overwrites
        gemm(AhiP, AloP, bthi[l][2], btlo[l][2], nullptr, zbuf, NP, MPAD_P, K, 2, 512, 512);
        // paper decomp for next layer / final linear
        decomp4_kernel<<<((size_t)MPAD_P * 512 / 4 + 255) / 256, 256, 0, stream>>>(
            (const float4*)hp_n, (ushort4*)AhiP, (ushort4*)AloP, NP, 512, MPAD_P);
        // author aggregation (wb) (+relu +fused decomp)
        eler_kernel<<<(NP + 3) / 4, 256, 0, stream>>>(zbuf, al + 1024, nullptr, elA, nullptr, NP);
        fold_kernel<<<(K * 4 + 255) / 256, 256, 0, stream>>>(W + 2 * wstride, ar + 1024, vfold, K);
        skinny_kernel<<<(NA + 3) / 4, 256, 0, stream>>>(ha, vfold, erA, NA, K);
        agg_fused<<<(NA + 3) / 4, 256, 0, stream>>>(
            rp_b, col_b, zbuf, elA, erA,
            nullptr, nullptr, nullptr, nullptr, nullptr,
            ha_n, (l < 2) ? AhiA : nullptr, (l < 2) ? AloA : nullptr, NA, relu);
        hp = hp_n;
        ha = ha_n;
    }
    // ---- final linear ----
    gemm(AhiP, AloP, btLhi, btLlo, linb, out, NP, MPAD_P, 512, 1, NCLS, NCLS);
}